// Round 11
// baseline (200.004 us; speedup 1.0000x reference)
//
#include <hip/hip_runtime.h>
#include <math.h>

typedef __attribute__((ext_vector_type(8))) short bf16x8;   // 8 bf16 (4 VGPRs)
typedef __attribute__((ext_vector_type(4))) float f32x4;    // MFMA acc

#define SQRT3F     1.7320508075688772f
#define SCALE_T    0.17677669529663687f    // 1/sqrt(32)
#define SCALE_M1   0.025515518153991442f   // C_SCALAR/sqrt(32)
#define SCALE_M2   0.014731391274719739f   // C_SCALAR*inv_sqrt3/sqrt(32)
#define SCALE_M34  0.036084391824351615f   // C_SCALAR/4

#define FSTR 40    // feature row stride (shorts): 80 B, 16B-aligned rows
#define ASTR 72    // agg / M row stride (shorts): 144 B, 16B-aligned rows

__device__ __forceinline__ ushort f2bf(float f) {
    union { float f; unsigned u; } v; v.f = f;
    unsigned u = v.u;
    return (ushort)((u + 0x7FFFu + ((u >> 16) & 1u)) >> 16);
}
__device__ __forceinline__ float bf2f(ushort h) {
    union { unsigned u; float f; } v; v.u = ((unsigned)h) << 16;
    return v.f;
}
__device__ __forceinline__ f32x4 mfma(bf16x8 a, bf16x8 b, f32x4 c) {
    return __builtin_amdgcn_mfma_f32_16x16x32_bf16(a, b, c, 0, 0, 0);
}
// D-tile -> agg[n][u0..u0+3] (4 consecutive u = 8 B), bf16
__device__ __forceinline__ void storeAgg(ushort* AG, f32x4 t, int u0, int n) {
    uint2 u;
    u.x = f2bf(t[0]) | ((unsigned)f2bf(t[1]) << 16);
    u.y = f2bf(t[2]) | ((unsigned)f2bf(t[3]) << 16);
    *(uint2*)&AG[n*ASTR + u0] = u;
}

// ---------------------------------------------------------------------------
// Fully fused: weight-fold + embedding + adjacency + 3 MFMA layers + pool +
// MLP head, one dispatch. One wave = one graph (32 nodes); 4 graphs/block.
// LDS: lM (folded M, bf16, block-shared) | feat (per-wave, bf16, transposed)
//    | agg (per-wave scratch; after layers reused as MLP h1/red) | hgl.
// Fragment scheme = verified m89 "B^T" GEMM (round-10 validated): A row
// m=l&15, B row n=l&15, both k=(l>>4)*8 contiguous; D col=l&15,
// row=(l>>4)*4+reg.
// ---------------------------------------------------------------------------
__global__ __launch_bounds__(256)
void gnn_kernel(const float* __restrict__ pos, const int* __restrict__ z,
                const float* __restrict__ emb, const float* __restrict__ W_s2n,
                const float* __restrict__ W1, const float* __restrict__ W2,
                const float* __restrict__ W3, const float* __restrict__ W4,
                const float* __restrict__ Ws, const float* __restrict__ Wv,
                const float* __restrict__ Wr1, const float* __restrict__ br1,
                const float* __restrict__ Wr2, const float* __restrict__ br2,
                float* __restrict__ out, int B)
{
    __shared__ __align__(16) char smem[66048];
    ushort* lM    = (ushort*)smem;                    // 3*48*72*2 = 20736 B
    ushort* featA = (ushort*)(smem + 20736);          // 4*80*40*2 = 25600 B
    ushort* aggA  = (ushort*)(smem + 46336);          // 4*32*72*2 = 18432 B
    float*  hgl   = (float*)(smem + 64768);           // 4*80*4    = 1280 B
    float*  h1    = (float*)aggA;                     // alias (post-layers)
    float*  red   = ((float*)aggA) + 1024;            // alias, +4096 B

    const int tid = threadIdx.x;

    // --- block-redundant weight fold -> lM (bf16, transposed M) ---
    for (int idx = tid; idx < 3*48*64; idx += 256) {
        int lyr = idx / 3072, rem = idx % 3072;
        int row = rem >> 6, u = rem & 63;
        float val = 0.f;
        if (row < 32) {
            int w = row;
            if (u < 32) {
                float a = 0.f;
                for (int k = 0; k < 32; ++k)
                    a += W1[lyr*1024 + u*32 + k] * Ws[lyr*1024 + k*32 + w];
                val = a * SCALE_M1;
            } else if (u < 48) {
                int uu = u - 32; float a = 0.f;
                for (int k = 0; k < 32; ++k)
                    a += W4[lyr*512 + uu*32 + k] * Ws[lyr*1024 + k*32 + w];
                val = a * SCALE_M2;
            }
        } else {
            int w = row - 32;
            if (u < 32) {
                float a = 0.f;
                for (int k = 0; k < 16; ++k)
                    a += W2[lyr*512 + u*16 + k] * Wv[lyr*256 + k*16 + w];
                val = a * SCALE_M34;
            } else if (u < 48) {
                int uu = u - 32; float a = 0.f;
                for (int k = 0; k < 16; ++k)
                    a += W3[lyr*256 + uu*16 + k] * Wv[lyr*256 + k*16 + w];
                val = a * SCALE_M34;
            }
        }
        lM[lyr*48*ASTR + row*ASTR + u] = f2bf(val);
    }

    const int wv = tid >> 6, l = tid & 63;
    const int g  = blockIdx.x*4 + wv;
    ushort* F  = featA + wv*80*FSTR;
    ushort* AG = aggA  + wv*32*ASTR;

    // zero agg (incl. K-pad cols 48..63) and v feature rows
    for (int i = l; i < 32*(ASTR/2); i += 64) ((uint*)AG)[i] = 0;
    for (int i = l; i < 48*(FSTR/2); i += 64) ((uint*)(F + 32*FSTR))[i] = 0;

    // --- s init (inline T = emb @ W_s2n * sT), stored transposed bf16 ---
    {
        int n = l & 31, h = l >> 5;
        int zg = z[g*32 + n];
        const float* er = emb + (size_t)zg*32;
        for (int cc = 0; cc < 16; ++cc) {
            int c = h*16 + cc;
            float acc = 0.f;
            for (int k = 0; k < 32; ++k) acc += er[k] * W_s2n[k*32 + c];
            F[c*FSTR + n] = f2bf(acc * SCALE_T);
        }
    }

    // --- adjacency fragments inline (layer-invariant, 32 VGPRs) ---
    const int ln = l & 15, kq = l >> 4;
    bf16x8 adjf[4][2];
    {
        const int k0 = kq*8;
        #pragma unroll
        for (int nt = 0; nt < 2; ++nt) {
            int ng = g*32 + nt*16 + ln;
            float px = pos[3*ng], py = pos[3*ng+1], pz = pos[3*ng+2];
            union { bf16x8 v; ushort s[8]; } o[4];
            #pragma unroll
            for (int jj = 0; jj < 8; ++jj) {
                int j = g*32 + k0 + jj;
                float dx = __fsub_rn(px, pos[3*j]);
                float dy = __fsub_rn(py, pos[3*j+1]);
                float dz = __fsub_rn(pz, pos[3*j+2]);
                float d2 = __fadd_rn(__fadd_rn(__fmul_rn(dx,dx), __fmul_rn(dy,dy)),
                                     __fmul_rn(dz,dz));
                bool on = (d2 <= 25.0f) && (d2 > 0.0f);
                float rinv = on ? rsqrtf(d2) * SQRT3F : 0.f;
                o[0].s[jj] = on ? (ushort)0x3F80 : (ushort)0;   // bf16(1.0)
                o[1].s[jj] = f2bf(dx * rinv);
                o[2].s[jj] = f2bf(dy * rinv);
                o[3].s[jj] = f2bf(dz * rinv);
            }
            #pragma unroll
            for (int w = 0; w < 4; ++w) adjf[w][nt] = o[w].v;
        }
    }
    __syncthreads();   // lM ready

    const f32x4 z4 = {0.f, 0.f, 0.f, 0.f};

    for (int lay = 0; lay < 3; ++lay) {
        const ushort* Msl = lM + lay*48*ASTR;
        // feature fragments (pre-update values)
        bf16x8 fs0 = *(const bf16x8*)&F[(     ln)*FSTR + kq*8];
        bf16x8 fs1 = *(const bf16x8*)&F[(16 + ln)*FSTR + kq*8];
        bf16x8 fv0 = *(const bf16x8*)&F[(32 + ln)*FSTR + kq*8];
        bf16x8 fv1 = *(const bf16x8*)&F[(48 + ln)*FSTR + kq*8];
        bf16x8 fv2 = *(const bf16x8*)&F[(64 + ln)*FSTR + kq*8];

        // ---- scalar path: agg = [A0 (u<32) | a3 (u 32..47)]
        #pragma unroll
        for (int nt = 0; nt < 2; ++nt) {
            f32x4 t;
            t = mfma(fs0, adjf[0][nt], z4);
            storeAgg(AG, t,      kq*4, nt*16 + ln);
            t = mfma(fs1, adjf[0][nt], z4);
            storeAgg(AG, t, 16 + kq*4, nt*16 + ln);
            t = mfma(fv2, adjf[3][nt], z4);
            t = mfma(fv1, adjf[2][nt], t);
            t = mfma(fv0, adjf[1][nt], t);
            storeAgg(AG, t, 32 + kq*4, nt*16 + ln);
        }
        f32x4 hs[2][2] = {{z4, z4}, {z4, z4}};
        #pragma unroll
        for (int kc = 0; kc < 2; ++kc) {
            bf16x8 m0 = *(const bf16x8*)&Msl[(     ln)*ASTR + kc*32 + kq*8];
            bf16x8 m1 = *(const bf16x8*)&Msl[(16 + ln)*ASTR + kc*32 + kq*8];
            #pragma unroll
            for (int nt = 0; nt < 2; ++nt) {
                bf16x8 bg = *(const bf16x8*)&AG[(nt*16 + ln)*ASTR + kc*32 + kq*8];
                hs[0][nt] = mfma(m0, bg, hs[0][nt]);
                hs[1][nt] = mfma(m1, bg, hs[1][nt]);
            }
        }
        #pragma unroll
        for (int mt = 0; mt < 2; ++mt)
            #pragma unroll
            for (int nt = 0; nt < 2; ++nt) {
                int n = nt*16 + ln;
                #pragma unroll
                for (int r = 0; r < 4; ++r) {
                    int c = mt*16 + kq*4 + r;
                    ushort* p = &F[c*FSTR + n];
                    *p = f2bf(bf2f(*p) + fmaxf(hs[mt][nt][r], 0.f));
                }
            }

        // ---- vector path, one spatial component i at a time (reuses AG)
        #pragma unroll
        for (int i = 0; i < 3; ++i) {
            bf16x8 fvi = (i == 0) ? fv0 : (i == 1) ? fv1 : fv2;
            #pragma unroll
            for (int nt = 0; nt < 2; ++nt) {
                f32x4 t;
                t = mfma(fs0, adjf[1+i][nt], z4);
                storeAgg(AG, t,      kq*4, nt*16 + ln);
                t = mfma(fs1, adjf[1+i][nt], z4);
                storeAgg(AG, t, 16 + kq*4, nt*16 + ln);
                t = mfma(fvi, adjf[0][nt], z4);
                storeAgg(AG, t, 32 + kq*4, nt*16 + ln);
            }
            f32x4 hv[2] = {z4, z4};
            #pragma unroll
            for (int kc = 0; kc < 2; ++kc) {
                bf16x8 mv = *(const bf16x8*)&Msl[(32 + ln)*ASTR + kc*32 + kq*8];
                #pragma unroll
                for (int nt = 0; nt < 2; ++nt) {
                    bf16x8 bg = *(const bf16x8*)&AG[(nt*16 + ln)*ASTR + kc*32 + kq*8];
                    hv[nt] = mfma(mv, bg, hv[nt]);
                }
            }
            #pragma unroll
            for (int nt = 0; nt < 2; ++nt) {
                int n = nt*16 + ln;
                #pragma unroll
                for (int r = 0; r < 4; ++r) {
                    int c = 32 + i*16 + kq*4 + r;
                    ushort* p = &F[c*FSTR + n];
                    *p = f2bf(bf2f(*p) + fmaxf(hv[nt][r], 0.f));
                }
            }
        }
    }

    // --- wave-local sum-pool -> hgl[wv][80] ---
    for (int f = l; f < 80; f += 64) {
        const ushort* row;
        if (f < 32) row = &F[f*FSTR];
        else { int c = f - 32, w = c/3, i = c - 3*w; row = &F[(32 + i*16 + w)*FSTR]; }
        const uint* r32 = (const uint*)row;
        float acc = 0.f;
        #pragma unroll
        for (int q = 0; q < 16; ++q) {
            uint u = r32[q];
            acc += bf2f((ushort)u) + bf2f((ushort)(u >> 16));
        }
        hgl[wv*80 + f] = acc;
    }
    __syncthreads();   // all waves done with agg; hgl complete

    // --- fused MLP head (block = its 4 graphs) ---
    {
        const int w = tid;
        float acc0 = br1[w];
        float acc1 = acc0, acc2 = acc0, acc3 = acc0;
        #pragma unroll 4
        for (int f = 0; f < 80; ++f) {
            float wvv = Wr1[f*256 + w];
            acc0 = fmaf(hgl[0*80 + f], wvv, acc0);
            acc1 = fmaf(hgl[1*80 + f], wvv, acc1);
            acc2 = fmaf(hgl[2*80 + f], wvv, acc2);
            acc3 = fmaf(hgl[3*80 + f], wvv, acc3);
        }
        h1[0*256 + w] = fmaxf(acc0, 0.f);
        h1[1*256 + w] = fmaxf(acc1, 0.f);
        h1[2*256 + w] = fmaxf(acc2, 0.f);
        h1[3*256 + w] = fmaxf(acc3, 0.f);
    }
    __syncthreads();
    {
        const int g0 = blockIdx.x * 4;
        const int w2 = tid & 127, kh = tid >> 7;
        const float4* h1v = (const float4*)h1;   // [4][64] float4 view
        float s0 = 0.f, s1 = 0.f, s2 = 0.f, s3 = 0.f;
        #pragma unroll 2
        for (int k4 = kh*32; k4 < kh*32 + 32; ++k4) {
            float4 hA = h1v[0*64 + k4];
            float4 hB = h1v[1*64 + k4];
            float4 hC = h1v[2*64 + k4];
            float4 hD = h1v[3*64 + k4];
            int k = k4 * 4;
            float m0 = Wr2[(size_t)(k+0)*128 + w2];
            float m1 = Wr2[(size_t)(k+1)*128 + w2];
            float m2 = Wr2[(size_t)(k+2)*128 + w2];
            float m3 = Wr2[(size_t)(k+3)*128 + w2];
            s0 = fmaf(hA.x,m0, fmaf(hA.y,m1, fmaf(hA.z,m2, fmaf(hA.w,m3, s0))));
            s1 = fmaf(hB.x,m0, fmaf(hB.y,m1, fmaf(hB.z,m2, fmaf(hB.w,m3, s1))));
            s2 = fmaf(hC.x,m0, fmaf(hC.y,m1, fmaf(hC.z,m2, fmaf(hC.w,m3, s2))));
            s3 = fmaf(hD.x,m0, fmaf(hD.y,m1, fmaf(hD.z,m2, fmaf(hD.w,m3, s3))));
        }
        if (kh) {
            red[0*128 + w2] = s0; red[1*128 + w2] = s1;
            red[2*128 + w2] = s2; red[3*128 + w2] = s3;
        }
        __syncthreads();
        if (!kh) {
            float b = br2[w2];
            out[(size_t)(g0+0)*128 + w2] = s0 + red[0*128 + w2] + b;
            out[(size_t)(g0+1)*128 + w2] = s1 + red[1*128 + w2] + b;
            out[(size_t)(g0+2)*128 + w2] = s2 + red[2*128 + w2] + b;
            out[(size_t)(g0+3)*128 + w2] = s3 + red[3*128 + w2] + b;
        }
    }
}

// ---------------------------------------------------------------------------
extern "C" void kernel_launch(void* const* d_in, const int* in_sizes, int n_in,
                              void* d_out, int out_size, void* d_ws, size_t ws_size,
                              hipStream_t stream)
{
    const float* pos   = (const float*)d_in[0];
    const int*   z     = (const int*)d_in[1];
    const float* emb   = (const float*)d_in[5];
    const float* W_s2n = (const float*)d_in[6];
    const float* W1    = (const float*)d_in[7];
    const float* W2    = (const float*)d_in[8];
    const float* W3    = (const float*)d_in[9];
    const float* W4    = (const float*)d_in[10];
    const float* Ws    = (const float*)d_in[11];
    const float* Wv    = (const float*)d_in[12];
    const float* Wr1   = (const float*)d_in[13];
    const float* br1   = (const float*)d_in[14];
    const float* Wr2   = (const float*)d_in[15];
    const float* br2   = (const float*)d_in[16];
    float* out = (float*)d_out;

    const int B = out_size / 128;      // graphs (2048)

    gnn_kernel<<<B / 4, 256, 0, stream>>>(pos, z, emb, W_s2n, W1, W2, W3, W4,
                                          Ws, Wv, Wr1, br1, Wr2, br2, out, B);
}

// Round 12
// 115.725 us; speedup vs baseline: 1.7283x; 1.7283x over previous
//
#include <hip/hip_runtime.h>
#include <math.h>

typedef __attribute__((ext_vector_type(8))) short bf16x8;   // 8 bf16 (4 VGPRs)
typedef __attribute__((ext_vector_type(4))) float f32x4;    // MFMA acc

#define SQRT3F     1.7320508075688772f
#define SCALE_T    0.17677669529663687f    // 1/sqrt(32)
#define SCALE_M1   0.025515518153991442f   // C_SCALAR/sqrt(32)
#define SCALE_M2   0.014731391274719739f   // C_SCALAR*inv_sqrt3/sqrt(32)
#define SCALE_M34  0.036084391824351615f   // C_SCALAR/4

#define FSTR 40    // feature row stride (shorts): 80 B
#define ASTR 72    // agg row stride (shorts): 144 B (16B-aligned, bank-spread)

__device__ __forceinline__ ushort f2bf(float f) {
    union { float f; unsigned u; } v; v.f = f;
    unsigned u = v.u;
    return (ushort)((u + 0x7FFFu + ((u >> 16) & 1u)) >> 16);
}
__device__ __forceinline__ float bf2f(ushort h) {
    union { unsigned u; float f; } v; v.u = ((unsigned)h) << 16;
    return v.f;
}
__device__ __forceinline__ f32x4 mfma(bf16x8 a, bf16x8 b, f32x4 c) {
    return __builtin_amdgcn_mfma_f32_16x16x32_bf16(a, b, c, 0, 0, 0);
}
// stage-1 D-tile -> agg[n][u0..u0+3] (4 consecutive u), bf16 packed
__device__ __forceinline__ void storeAgg(ushort* AG, f32x4 t, int u0, int n) {
    uint2 u;
    u.x = f2bf(t[0]) | ((unsigned)f2bf(t[1]) << 16);
    u.y = f2bf(t[2]) | ((unsigned)f2bf(t[3]) << 16);
    *(uint2*)&AG[n*ASTR + u0] = u;
}
// residual + relu RMW of 4 consecutive nodes at channel c (packed uint2)
__device__ __forceinline__ void rmw4(ushort* F, int c, int n0, f32x4 h) {
    uint2* p = (uint2*)&F[c*FSTR + n0];
    uint2 o = *p;
    float f0 = bf2f((ushort)(o.x      )) + fmaxf(h[0], 0.f);
    float f1 = bf2f((ushort)(o.x >> 16)) + fmaxf(h[1], 0.f);
    float f2 = bf2f((ushort)(o.y      )) + fmaxf(h[2], 0.f);
    float f3 = bf2f((ushort)(o.y >> 16)) + fmaxf(h[3], 0.f);
    uint2 w;
    w.x = f2bf(f0) | ((unsigned)f2bf(f1) << 16);
    w.y = f2bf(f2) | ((unsigned)f2bf(f3) << 16);
    *p = w;
}

// ---------------------------------------------------------------------------
// Prep (tiny, one-shot): Tbf = bf16(emb@W_s2n * sT)  (100x32)
//   Mbf[lyr][row][64]: rows 0..31 = MsT[w][u], rows 32..47 = MvT[w][u],
//   cols 48..63 zero (K-pad). Executed ONCE — round-11's block-redundant
//   in-kernel fold serialized the TA unit (64 lines/instr x 512 blocks).
// ---------------------------------------------------------------------------
__global__ void prep_kernel(const float* __restrict__ emb,
                            const float* __restrict__ W_s2n,
                            const float* __restrict__ W1, const float* __restrict__ W2,
                            const float* __restrict__ W3, const float* __restrict__ W4,
                            const float* __restrict__ Ws, const float* __restrict__ Wv,
                            ushort* __restrict__ Tbf, ushort* __restrict__ Mbf)
{
    int idx = blockIdx.x * blockDim.x + threadIdx.x;
    if (idx < 3200) {
        int r = idx >> 5, c = idx & 31;
        float acc = 0.f;
        for (int k = 0; k < 32; ++k) acc += emb[r*32 + k] * W_s2n[k*32 + c];
        Tbf[idx] = f2bf(acc * SCALE_T);
        return;
    }
    idx -= 3200;
    if (idx < 3*48*64) {
        int lyr = idx / 3072, rem = idx % 3072;
        int row = rem >> 6, u = rem & 63;
        float val = 0.f;
        if (row < 32) {
            int w = row;
            if (u < 32) {
                float a = 0.f;
                for (int k = 0; k < 32; ++k)
                    a += W1[lyr*1024 + u*32 + k] * Ws[lyr*1024 + k*32 + w];
                val = a * SCALE_M1;
            } else if (u < 48) {
                int uu = u - 32; float a = 0.f;
                for (int k = 0; k < 32; ++k)
                    a += W4[lyr*512 + uu*32 + k] * Ws[lyr*1024 + k*32 + w];
                val = a * SCALE_M2;
            }
        } else {
            int w = row - 32;
            if (u < 32) {
                float a = 0.f;
                for (int k = 0; k < 16; ++k)
                    a += W2[lyr*512 + u*16 + k] * Wv[lyr*256 + k*16 + w];
                val = a * SCALE_M34;
            } else if (u < 48) {
                int uu = u - 32; float a = 0.f;
                for (int k = 0; k < 16; ++k)
                    a += W3[lyr*256 + uu*16 + k] * Wv[lyr*256 + k*16 + w];
                val = a * SCALE_M34;
            }
        }
        Mbf[lyr*3072 + row*64 + u] = f2bf(val);
    }
}

// ---------------------------------------------------------------------------
// Fused GNN + MLP: one wave = one graph; 4 graphs/block; 512 blocks.
// LDS 44.2 KB -> 3 blocks/CU (12 waves). Layer loop is wave-private (no
// barriers). M fragments read from global Mbf (L1-hot, preloaded/layer).
// Stage 1: agg[n][u] = feat x Adj^T (m89 scheme, D col=n, rows=u).
// Stage 2 FLIPPED: mfma(agg_frag, M_frag) -> D col=w, rows=node -> packed
// uint2 residual RMW (4 bf16/op) instead of scalar ds RMWs.
// ---------------------------------------------------------------------------
__global__ __launch_bounds__(256)
void gnn_kernel(const float* __restrict__ pos, const int* __restrict__ z,
                const ushort* __restrict__ Tbf, const ushort* __restrict__ Mbf,
                const float* __restrict__ Wr1, const float* __restrict__ br1,
                const float* __restrict__ Wr2, const float* __restrict__ br2,
                float* __restrict__ out, int B)
{
    __shared__ __align__(16) char smem[45312];
    ushort* featA = (ushort*)smem;                    // 4*80*40*2 = 25600 B
    ushort* aggA  = (ushort*)(smem + 25600);          // 4*32*72*2 = 18432 B
    float*  hgl   = (float*)(smem + 44032);           // 4*80*4    = 1280 B
    float*  h1    = (float*)aggA;                     // alias (post-layers)
    float*  red   = ((float*)aggA) + 1024;            // alias, +4096 B

    const int tid = threadIdx.x;
    const int wv = tid >> 6, l = tid & 63;
    const int g  = blockIdx.x*4 + wv;
    ushort* F  = featA + wv*80*FSTR;
    ushort* AG = aggA  + wv*32*ASTR;

    // zero agg (incl. K-pad cols 48..63) and v feature rows
    for (int i = l; i < 32*(ASTR/2); i += 64) ((uint*)AG)[i] = 0;
    for (int i = l; i < 48*(FSTR/2); i += 64) ((uint*)(F + 32*FSTR))[i] = 0;

    // s init: F[c][n] = Tbf[z[n]][c]  (transposed scatter)
    {
        int n = l & 31, h = l >> 5;
        int zg = z[g*32 + n];
        uint4 t0 = *(const uint4*)(Tbf + zg*32 + h*16);
        uint4 t1 = *(const uint4*)(Tbf + zg*32 + h*16 + 8);
        unsigned ua[8] = {t0.x, t0.y, t0.z, t0.w, t1.x, t1.y, t1.z, t1.w};
        #pragma unroll
        for (int q = 0; q < 8; ++q) {
            F[(h*16 + 2*q    )*FSTR + n] = (ushort)ua[q];
            F[(h*16 + 2*q + 1)*FSTR + n] = (ushort)(ua[q] >> 16);
        }
    }

    // adjacency fragments inline (layer-invariant, 32 VGPRs)
    const int ln = l & 15, kq = l >> 4;
    bf16x8 adjf[4][2];
    {
        const int k0 = kq*8;
        #pragma unroll
        for (int nt = 0; nt < 2; ++nt) {
            int ng = g*32 + nt*16 + ln;
            float px = pos[3*ng], py = pos[3*ng+1], pz = pos[3*ng+2];
            union { bf16x8 v; ushort s[8]; } o[4];
            #pragma unroll
            for (int jj = 0; jj < 8; ++jj) {
                int j = g*32 + k0 + jj;
                float dx = __fsub_rn(px, pos[3*j]);
                float dy = __fsub_rn(py, pos[3*j+1]);
                float dz = __fsub_rn(pz, pos[3*j+2]);
                float d2 = __fadd_rn(__fadd_rn(__fmul_rn(dx,dx), __fmul_rn(dy,dy)),
                                     __fmul_rn(dz,dz));
                bool on = (d2 <= 25.0f) && (d2 > 0.0f);
                float rinv = on ? rsqrtf(d2) * SQRT3F : 0.f;
                o[0].s[jj] = on ? (ushort)0x3F80 : (ushort)0;   // bf16(1.0)
                o[1].s[jj] = f2bf(dx * rinv);
                o[2].s[jj] = f2bf(dy * rinv);
                o[3].s[jj] = f2bf(dz * rinv);
            }
            #pragma unroll
            for (int w = 0; w < 4; ++w) adjf[w][nt] = o[w].v;
        }
    }

    const f32x4 z4 = {0.f, 0.f, 0.f, 0.f};

    for (int lay = 0; lay < 3; ++lay) {
        const ushort* Mg = Mbf + lay*3072;
        // feature fragments (pre-update values)
        bf16x8 fs0 = *(const bf16x8*)&F[(     ln)*FSTR + kq*8];
        bf16x8 fs1 = *(const bf16x8*)&F[(16 + ln)*FSTR + kq*8];
        bf16x8 fv0 = *(const bf16x8*)&F[(32 + ln)*FSTR + kq*8];
        bf16x8 fv1 = *(const bf16x8*)&F[(48 + ln)*FSTR + kq*8];
        bf16x8 fv2 = *(const bf16x8*)&F[(64 + ln)*FSTR + kq*8];
        // M fragments for this layer (global, L1-hot)
        bf16x8 bmS0[2], bmS1[2], bmV[2];
        #pragma unroll
        for (int kc = 0; kc < 2; ++kc) {
            bmS0[kc] = *(const bf16x8*)&Mg[(     ln)*64 + kc*32 + kq*8];
            bmS1[kc] = *(const bf16x8*)&Mg[(16 + ln)*64 + kc*32 + kq*8];
            bmV [kc] = *(const bf16x8*)&Mg[(32 + ln)*64 + kc*32 + kq*8];
        }

        // ---- scalar path: agg = [A0 (u<32) | a3 (u 32..47)]
        #pragma unroll
        for (int nt = 0; nt < 2; ++nt) {
            f32x4 t;
            t = mfma(fs0, adjf[0][nt], z4);
            storeAgg(AG, t,      kq*4, nt*16 + ln);
            t = mfma(fs1, adjf[0][nt], z4);
            storeAgg(AG, t, 16 + kq*4, nt*16 + ln);
            t = mfma(fv2, adjf[3][nt], z4);
            t = mfma(fv1, adjf[2][nt], t);
            t = mfma(fv0, adjf[1][nt], t);
            storeAgg(AG, t, 32 + kq*4, nt*16 + ln);
        }
        f32x4 hs[2][2] = {{z4, z4}, {z4, z4}};   // [node-tile][w-tile]
        #pragma unroll
        for (int kc = 0; kc < 2; ++kc)
            #pragma unroll
            for (int mt = 0; mt < 2; ++mt) {
                bf16x8 ag = *(const bf16x8*)&AG[(mt*16 + ln)*ASTR + kc*32 + kq*8];
                hs[mt][0] = mfma(ag, bmS0[kc], hs[mt][0]);
                hs[mt][1] = mfma(ag, bmS1[kc], hs[mt][1]);
            }
        #pragma unroll
        for (int mt = 0; mt < 2; ++mt)
            #pragma unroll
            for (int wt = 0; wt < 2; ++wt)
                rmw4(F, wt*16 + ln, mt*16 + kq*4, hs[mt][wt]);

        // ---- vector path, one spatial component i at a time (reuses AG)
        #pragma unroll
        for (int i = 0; i < 3; ++i) {
            bf16x8 fvi = (i == 0) ? fv0 : (i == 1) ? fv1 : fv2;
            #pragma unroll
            for (int nt = 0; nt < 2; ++nt) {
                f32x4 t;
                t = mfma(fs0, adjf[1+i][nt], z4);
                storeAgg(AG, t,      kq*4, nt*16 + ln);
                t = mfma(fs1, adjf[1+i][nt], z4);
                storeAgg(AG, t, 16 + kq*4, nt*16 + ln);
                t = mfma(fvi, adjf[0][nt], z4);
                storeAgg(AG, t, 32 + kq*4, nt*16 + ln);
            }
            f32x4 hv[2] = {z4, z4};
            #pragma unroll
            for (int kc = 0; kc < 2; ++kc)
                #pragma unroll
                for (int mt = 0; mt < 2; ++mt) {
                    bf16x8 ag = *(const bf16x8*)&AG[(mt*16 + ln)*ASTR + kc*32 + kq*8];
                    hv[mt] = mfma(ag, bmV[kc], hv[mt]);
                }
            #pragma unroll
            for (int mt = 0; mt < 2; ++mt)
                rmw4(F, 32 + i*16 + ln, mt*16 + kq*4, hv[mt]);
        }
    }

    // wave-local sum-pool -> hgl[wv][80]
    for (int f = l; f < 80; f += 64) {
        const ushort* row;
        if (f < 32) row = &F[f*FSTR];
        else { int c = f - 32, w = c/3, i = c - 3*w; row = &F[(32 + i*16 + w)*FSTR]; }
        const uint* r32 = (const uint*)row;
        float acc = 0.f;
        #pragma unroll
        for (int q = 0; q < 16; ++q) {
            uint u = r32[q];
            acc += bf2f((ushort)u) + bf2f((ushort)(u >> 16));
        }
        hgl[wv*80 + f] = acc;
    }
    __syncthreads();   // all waves done with agg; hgl complete

    // --- fused MLP head (block = its 4 graphs) ---
    {
        const int w = tid;
        float acc0 = br1[w];
        float acc1 = acc0, acc2 = acc0, acc3 = acc0;
        #pragma unroll 4
        for (int f = 0; f < 80; ++f) {
            float wvv = Wr1[f*256 + w];
            acc0 = fmaf(hgl[0*80 + f], wvv, acc0);
            acc1 = fmaf(hgl[1*80 + f], wvv, acc1);
            acc2 = fmaf(hgl[2*80 + f], wvv, acc2);
            acc3 = fmaf(hgl[3*80 + f], wvv, acc3);
        }
        h1[0*256 + w] = fmaxf(acc0, 0.f);
        h1[1*256 + w] = fmaxf(acc1, 0.f);
        h1[2*256 + w] = fmaxf(acc2, 0.f);
        h1[3*256 + w] = fmaxf(acc3, 0.f);
    }
    __syncthreads();
    {
        const int g0 = blockIdx.x * 4;
        const int w2 = tid & 127, kh = tid >> 7;
        const float4* h1v = (const float4*)h1;   // [4][64] float4 view
        float s0 = 0.f, s1 = 0.f, s2 = 0.f, s3 = 0.f;
        #pragma unroll 2
        for (int k4 = kh*32; k4 < kh*32 + 32; ++k4) {
            float4 hA = h1v[0*64 + k4];
            float4 hB = h1v[1*64 + k4];
            float4 hC = h1v[2*64 + k4];
            float4 hD = h1v[3*64 + k4];
            int k = k4 * 4;
            float m0 = Wr2[(size_t)(k+0)*128 + w2];
            float m1 = Wr2[(size_t)(k+1)*128 + w2];
            float m2 = Wr2[(size_t)(k+2)*128 + w2];
            float m3 = Wr2[(size_t)(k+3)*128 + w2];
            s0 = fmaf(hA.x,m0, fmaf(hA.y,m1, fmaf(hA.z,m2, fmaf(hA.w,m3, s0))));
            s1 = fmaf(hB.x,m0, fmaf(hB.y,m1, fmaf(hB.z,m2, fmaf(hB.w,m3, s1))));
            s2 = fmaf(hC.x,m0, fmaf(hC.y,m1, fmaf(hC.z,m2, fmaf(hC.w,m3, s2))));
            s3 = fmaf(hD.x,m0, fmaf(hD.y,m1, fmaf(hD.z,m2, fmaf(hD.w,m3, s3))));
        }
        if (kh) {
            red[0*128 + w2] = s0; red[1*128 + w2] = s1;
            red[2*128 + w2] = s2; red[3*128 + w2] = s3;
        }
        __syncthreads();
        if (!kh) {
            float b = br2[w2];
            out[(size_t)(g0+0)*128 + w2] = s0 + red[0*128 + w2] + b;
            out[(size_t)(g0+1)*128 + w2] = s1 + red[1*128 + w2] + b;
            out[(size_t)(g0+2)*128 + w2] = s2 + red[2*128 + w2] + b;
            out[(size_t)(g0+3)*128 + w2] = s3 + red[3*128 + w2] + b;
        }
    }
}

// ---------------------------------------------------------------------------
extern "C" void kernel_launch(void* const* d_in, const int* in_sizes, int n_in,
                              void* d_out, int out_size, void* d_ws, size_t ws_size,
                              hipStream_t stream)
{
    const float* pos   = (const float*)d_in[0];
    const int*   z     = (const int*)d_in[1];
    const float* emb   = (const float*)d_in[5];
    const float* W_s2n = (const float*)d_in[6];
    const float* W1    = (const float*)d_in[7];
    const float* W2    = (const float*)d_in[8];
    const float* W3    = (const float*)d_in[9];
    const float* W4    = (const float*)d_in[10];
    const float* Ws    = (const float*)d_in[11];
    const float* Wv    = (const float*)d_in[12];
    const float* Wr1   = (const float*)d_in[13];
    const float* br1   = (const float*)d_in[14];
    const float* Wr2   = (const float*)d_in[15];
    const float* br2   = (const float*)d_in[16];
    float* out = (float*)d_out;

    const int B = out_size / 128;      // graphs (2048)

    // workspace: Tbf (3200 shorts) | Mbf (9216 shorts)
    char* p = (char*)d_ws;
    ushort* Tbf = (ushort*)p;  p += 6400;
    ushort* Mbf = (ushort*)p;  p += 18432;

    const int prep_total = 3200 + 3*48*64;
    prep_kernel<<<(prep_total + 255) / 256, 256, 0, stream>>>(
        emb, W_s2n, W1, W2, W3, W4, Ws, Wv, Tbf, Mbf);

    gnn_kernel<<<B / 4, 256, 0, stream>>>(pos, z, Tbf, Mbf,
                                          Wr1, br1, Wr2, br2, out, B);
}